// Round 7
// baseline (696.492 us; speedup 1.0000x reference)
//
#include <hip/hip_runtime.h>
#include <hip/hip_bf16.h>

// Max-tree (component tree) per channel, 64x64x3. Outputs (float32):
// parents [3,4096] then altitudes [3,4096].
//
// ranks = stable descending sort position (distinct, 0 = highest f) act as
// altitudes; rank-image max-tree's uncompressed pixel-parent == reference's
// (validated r2-r6). Distinct ranks => UNIQUE tree => order-independent
// concurrent CAS-based ordered union (splice walk, validated r5/r6).
//
// NEW (r7): rank-phased schedule. Berger == Kruskal over edges sorted by
// ry = rank(higher endpoint); the splice walk is order-agnostic, so phasing
// only reduces conflicts/walk lengths. 64 barrier phases, phase ph handles
// edges with ry in [64ph, 64ph+64) (slot = 4*ry+k). Between phases a
// pointer-doubling sweep compresses skipw toward the settled frontier
// (guard rank < frontier => hint always jumpable by future walks, since
// ancestor ranks strictly ascend and future ry >= frontier). This bounds
// walk length to ~O(band) instead of O(tree depth) - r6's failure mode.
//
// parw[x] = (rank(parent(x))<<12)|parent(x); root: (rank(x)<<12)|x. CAS is
// ABA-safe: non-root parent-rank strictly decreases; root->attached once.
// skipw[x] = (rank(t)<<12)|t with t an ancestor of x (or x): splices only
// INSERT nodes into root paths => ancestorship persists; ranks ascend along
// root paths => jump safe whenever rank(t) <= ry. Plain 32b LDS stores are
// word-atomic; any racy hint is still a valid ancestor.
// Canon closed form g[p] = climb-from-parent-while-f-equal (validated r2-r6).

#define N_PIX 4096
#define CH 3

// ---------------------------------------------------------------------------
// K1: stable descending rank: rank(p) = #{f[q]>f[p]} + #{f[q]==f[p], q<p}
// ---------------------------------------------------------------------------
__global__ __launch_bounds__(256) void ct_rank(const float* __restrict__ vw,
                                               int* __restrict__ rank_g) {
    __shared__ __align__(16) float vals[N_PIX];
    const int c   = blockIdx.x >> 4;
    const int seg = blockIdx.x & 15;
    const int tid = threadIdx.x;
    for (int i = tid; i < N_PIX; i += 256) vals[i] = vw[i * CH + c];
    __syncthreads();

    const int   p  = (seg << 8) + tid;
    const float vp = vals[p];
    int cnt = 0;
    const float4* v4 = reinterpret_cast<const float4*>(vals);
#pragma unroll 4
    for (int j4 = 0; j4 < N_PIX / 4; ++j4) {
        float4 q = v4[j4];
        int j = j4 << 2;
        cnt += (q.x > vp) || ((q.x == vp) && (j     < p));
        cnt += (q.y > vp) || ((q.y == vp) && (j + 1 < p));
        cnt += (q.z > vp) || ((q.z == vp) && (j + 2 < p));
        cnt += (q.w > vp) || ((q.w == vp) && (j + 3 < p));
    }
    rank_g[(c << 12) + p] = cnt;
}

// ---------------------------------------------------------------------------
// K2: rank-phased concurrent ordered union + canon. 1 block/channel.
// ---------------------------------------------------------------------------
__global__ __launch_bounds__(1024) void ct_tree(const float* __restrict__ vw,
                                                const int* __restrict__ rank_g,
                                                float* __restrict__ out) {
    __shared__ unsigned       parw[N_PIX];     // 16 KB
    __shared__ unsigned       skipw[N_PIX];    // 16 KB
    __shared__ unsigned short rank16[N_PIX];   // 8 KB
    __shared__ unsigned short inv16[N_PIX];    // 8 KB  (inv16[rank] = pixel)
    const int c   = blockIdx.x;
    const int tid = threadIdx.x;

    for (int p = tid; p < N_PIX; p += 1024) {
        const unsigned r = (unsigned)rank_g[(c << 12) + p];
        rank16[p] = (unsigned short)r;
        inv16[r]  = (unsigned short)p;
        parw[p]   = (r << 12) | (unsigned)p;
        skipw[p]  = (r << 12) | (unsigned)p;   // self: no ancestor known yet
    }
    __syncthreads();

    volatile unsigned* vpar = parw;
    volatile unsigned* vskp = skipw;

    for (int ph = 0; ph < 64; ++ph) {
        // ---- walks: 256 slots = ranks [64ph, 64ph+64) x 4 neighbors ----
        if (tid < 256) {
            const int slot = (ph << 8) + tid;
            unsigned  ry   = (unsigned)(slot >> 2);
            const int k    = slot & 3;
            const int yy   = inv16[ry];
            const int row  = yy >> 6, col = yy & 63;
            int x; bool ok;
            if      (k == 0) { x = yy - 64; ok = row > 0;  }
            else if (k == 1) { x = yy + 64; ok = row < 63; }
            else if (k == 2) { x = yy - 1;  ok = col > 0;  }
            else             { x = yy + 1;  ok = col < 63; }
            if (ok && (unsigned)rank16[x] < ry) {
                int y = yy;
                // invariant: rank(x) < ry = rank(y); insert y into x's path.
                for (;;) {
                    // skip fast-forward with path-halving
                    unsigned sk = vskp[x];
                    for (;;) {
                        const unsigned s = sk & 0xFFFu;
                        if (s == (unsigned)x || (sk >> 12) > ry) break;
                        const unsigned sk2 = vskp[s];
                        if ((sk2 >> 12) <= ry && (sk2 & 0xFFFu) != s) skipw[x] = sk2;
                        x = (int)s; sk = sk2;
                    }
                    if (x == y) break;            // already linked
                    const unsigned w  = vpar[x];
                    const unsigned p  = w & 0xFFFu;
                    const unsigned rp = w >> 12;
                    if (p == (unsigned)x) {                   // root: attach y
                        if (atomicCAS(&parw[x], w, (ry << 12) | (unsigned)y) == w) {
                            skipw[x] = (ry << 12) | (unsigned)y;
                            break;
                        }
                    } else if (rp < ry) {                     // climb, memo
                        skipw[x] = w;
                        x = (int)p;
                    } else if (rp > ry) {                     // splice y below p
                        if (atomicCAS(&parw[x], w, (ry << 12) | (unsigned)y) == w) {
                            skipw[x] = (ry << 12) | (unsigned)y;
                            x = y; y = (int)p; ry = rp;       // keep inserting p
                        }
                    } else break;                             // rp==ry => p==y
                }
            }
        }
        __syncthreads();

        // ---- sweep: pointer-double skipw toward settled frontier ----
        const unsigned thr = (unsigned)((ph + 1) << 6);  // ranks < thr settled
        for (int n = tid; n < N_PIX; n += 1024) {
            unsigned sk = skipw[n];
            unsigned s  = sk & 0xFFFu;
            if (s == (unsigned)n) {              // self-hint: seed from parw
                sk = parw[n]; s = sk & 0xFFFu;
                if (s == (unsigned)n || (sk >> 12) >= thr) continue;
                skipw[n] = sk;
            }
            unsigned sk2 = skipw[s];
            if ((sk2 >> 12) < thr && (sk2 & 0xFFFu) != s) {
                const unsigned s2  = sk2 & 0xFFFu;
                const unsigned sk3 = skipw[s2];
                if ((sk3 >> 12) < thr && (sk3 & 0xFFFu) != s2) sk2 = sk3;
                skipw[n] = sk2;
            }
        }
        __syncthreads();
    }

    // canon (g[p] = climb-from-parent-while-f-equal, validated r2-r6) + output
    for (int p = tid; p < N_PIX; p += 1024) {
        int q = parw[p] & 0xFFF;
        const float fq = vw[q * CH + c];
        for (;;) {
            const int qp = parw[q] & 0xFFF;
            if (qp == q) break;
            if (vw[qp * CH + c] != fq) break;
            q = qp;
        }
        out[(c << 12) + p] = (float)q;
        out[CH * N_PIX + (c << 12) + p] = vw[p * CH + c];
    }
}

extern "C" void kernel_launch(void* const* d_in, const int* in_sizes, int n_in,
                              void* d_out, int out_size, void* d_ws, size_t ws_size,
                              hipStream_t stream) {
    const float* vw = (const float*)d_in[0];
    float* out = (float*)d_out;

    int* rank_g = (int*)d_ws;   // 3*4096 ints

    ct_rank<<<48, 256, 0, stream>>>(vw, rank_g);
    ct_tree<<<CH, 1024, 0, stream>>>(vw, rank_g, out);
}

// Round 8
// 441.783 us; speedup vs baseline: 1.5765x; 1.5765x over previous
//
#include <hip/hip_runtime.h>
#include <hip/hip_bf16.h>

// Max-tree (component tree) per channel, 64x64x3. Outputs (float32):
// parents [3,4096] then altitudes [3,4096].
//
// ranks = stable descending sort position (distinct, 0 = highest f) act as
// altitudes; rank-image max-tree's uncompressed pixel-parent == reference's
// (validated r2-r7). Distinct ranks => UNIQUE tree => order-independent
// concurrent CAS-based ordered union over all 8064 edges (validated r5-r7).
//
// r8: free-for-all schedule (r6) + 8-way INTERLEAVED walks per thread.
// Each thread keeps 8 walk states; phase A issues all skipw/parw loads
// (16 independent ds_reads in flight), phase B advances each walk one
// macro-step. Turns the per-thread serial latency chain (r6's bottleneck:
// ~240cy per dependent LDS step) into ~8-way MLP.
//
// Safety (r5/r6 arguments, interleaving-agnostic):
//  - parw[x] = (rank(parent)<<12)|parent; root holds (rank(x)<<12)|x. CAS is
//    ABA-safe: after first attach the stored parent-rank strictly decreases,
//    and the self-word never recurs => no value repeats.
//  - climb on stale w is safe: splices only INSERT between x and its parent,
//    so a once-read parent remains an ancestor forever.
//  - skipw[n] always holds (rank(t)<<12)|t with t an ancestor-or-self of n;
//    jump guarded by rank(t) <= ry (ranks ascend along root paths). Deferred
//    halving skipw[px] = skipw[x_new] is valid: ancestor of ancestor.
// Canon closed form g[p] = climb-from-parent-while-f-equal (validated r2-r7).

#define N_PIX 4096
#define CH 3

// ---------------------------------------------------------------------------
// K1: stable descending rank: rank(p) = #{f[q]>f[p]} + #{f[q]==f[p], q<p}
// ---------------------------------------------------------------------------
__global__ __launch_bounds__(256) void ct_rank(const float* __restrict__ vw,
                                               int* __restrict__ rank_g) {
    __shared__ __align__(16) float vals[N_PIX];
    const int c   = blockIdx.x >> 4;
    const int seg = blockIdx.x & 15;
    const int tid = threadIdx.x;
    for (int i = tid; i < N_PIX; i += 256) vals[i] = vw[i * CH + c];
    __syncthreads();

    const int   p  = (seg << 8) + tid;
    const float vp = vals[p];
    int cnt = 0;
    const float4* v4 = reinterpret_cast<const float4*>(vals);
#pragma unroll 4
    for (int j4 = 0; j4 < N_PIX / 4; ++j4) {
        float4 q = v4[j4];
        int j = j4 << 2;
        cnt += (q.x > vp) || ((q.x == vp) && (j     < p));
        cnt += (q.y > vp) || ((q.y == vp) && (j + 1 < p));
        cnt += (q.z > vp) || ((q.z == vp) && (j + 2 < p));
        cnt += (q.w > vp) || ((q.w == vp) && (j + 3 < p));
    }
    rank_g[(c << 12) + p] = cnt;
}

// ---------------------------------------------------------------------------
// K2: concurrent ordered union, 8-way interleaved walks + canon.
// One block per channel, 1024 threads, 8 edges per thread.
// ---------------------------------------------------------------------------
__global__ __launch_bounds__(1024) void ct_tree(const float* __restrict__ vw,
                                                const int* __restrict__ rank_g,
                                                float* __restrict__ out) {
    __shared__ unsigned       parw[N_PIX];     // 16 KB
    __shared__ unsigned       skipw[N_PIX];    // 16 KB
    __shared__ unsigned short rank16[N_PIX];   // 8 KB
    __shared__ float          vals[N_PIX];     // 16 KB (canon altitudes)
    const int c   = blockIdx.x;
    const int tid = threadIdx.x;

    for (int p = tid; p < N_PIX; p += 1024) {
        const unsigned r = (unsigned)rank_g[(c << 12) + p];
        rank16[p] = (unsigned short)r;
        parw[p]   = (r << 12) | (unsigned)p;
        skipw[p]  = (r << 12) | (unsigned)p;   // self: no ancestor known yet
        vals[p]   = vw[p * CH + c];
    }
    __syncthreads();

    volatile unsigned* vpar = parw;
    volatile unsigned* vskp = skipw;

    // ---- init 8 walk states (edges: horizontal id=row*63+col, vert after) --
    int xA[8], yA[8], ryA[8], pxA[8];
    unsigned act = 0;
#pragma unroll
    for (int k = 0; k < 8; ++k) {
        xA[k] = 0; yA[k] = 0; ryA[k] = 0; pxA[k] = -1;
        const int e = (k << 10) + tid;
        if (e < 8064) {
            int x, y;
            if (e < 4032) { const int row = e / 63; x = row * 64 + (e - row * 63); y = x + 1; }
            else          { const int e2 = e - 4032; x = ((e2 >> 6) << 6) + (e2 & 63); y = x + 64; }
            unsigned rx = rank16[x], ry = rank16[y];
            if (rx > ry) { int t = x; x = y; y = t; unsigned tr = rx; rx = ry; ry = tr; }
            xA[k] = x; yA[k] = y; ryA[k] = (int)ry;
            act |= 1u << k;
        }
    }

    // ---- interleaved macro-step loop ----
    while (act) {
        unsigned skL[8], wL[8];
#pragma unroll
        for (int k = 0; k < 8; ++k) {          // phase A: issue all loads
            skL[k] = vskp[xA[k]];
            wL[k]  = vpar[xA[k]];
        }
#pragma unroll
        for (int k = 0; k < 8; ++k) {          // phase B: advance one step
            if (!(act & (1u << k))) continue;
            const int      x  = xA[k];
            const unsigned ry = (unsigned)ryA[k];
            const unsigned sk = skL[k];
            if (pxA[k] >= 0) { skipw[pxA[k]] = sk; pxA[k] = -1; }  // deferred halving
            const unsigned s = sk & 0xFFFu;
            if (s != (unsigned)x && (sk >> 12) <= ry) {            // jump
                if (s == (unsigned)yA[k]) { act &= ~(1u << k); }
                else                      { pxA[k] = x; xA[k] = (int)s; }
                continue;
            }
            const unsigned w  = wL[k];
            const unsigned p  = w & 0xFFFu;
            const unsigned rp = w >> 12;
            if (p == (unsigned)x) {                                // root: attach y
                if (atomicCAS(&parw[x], w, (ry << 12) | (unsigned)yA[k]) == w) {
                    skipw[x] = (ry << 12) | (unsigned)yA[k];
                    act &= ~(1u << k);
                }
            } else if (rp < ry) {                                  // climb + memo
                skipw[x] = w;
                xA[k] = (int)p;
            } else if (rp > ry) {                                  // splice y below p
                if (atomicCAS(&parw[x], w, (ry << 12) | (unsigned)yA[k]) == w) {
                    skipw[x] = (ry << 12) | (unsigned)yA[k];
                    xA[k] = yA[k]; yA[k] = (int)p; ryA[k] = (int)rp;
                }
            } else { act &= ~(1u << k); }                          // rp==ry => p==y
        }
    }
    __syncthreads();

    // ---- canon (g[p] = climb-from-parent-while-f-equal) + output ----
    for (int p = tid; p < N_PIX; p += 1024) {
        int q = parw[p] & 0xFFF;
        const float fq = vals[q];
        for (;;) {
            const int qp = parw[q] & 0xFFF;
            if (qp == q) break;
            if (vals[qp] != fq) break;
            q = qp;
        }
        out[(c << 12) + p] = (float)q;
        out[CH * N_PIX + (c << 12) + p] = vals[p];
    }
}

extern "C" void kernel_launch(void* const* d_in, const int* in_sizes, int n_in,
                              void* d_out, int out_size, void* d_ws, size_t ws_size,
                              hipStream_t stream) {
    const float* vw = (const float*)d_in[0];
    float* out = (float*)d_out;

    int* rank_g = (int*)d_ws;   // 3*4096 ints

    ct_rank<<<48, 256, 0, stream>>>(vw, rank_g);
    ct_tree<<<CH, 1024, 0, stream>>>(vw, rank_g, out);
}